// Round 16
// baseline (91.406 us; speedup 1.0000x reference)
//
#include <hip/hip_runtime.h>
#include <hip/hip_bf16.h>

constexpr int BB = 4;
constexpr int SS = 1024;
constexpr int HH = 16;
constexpr int DH = 64;
constexpr int DM = 1024;

using f32x16 = __attribute__((ext_vector_type(16))) float;
using s16x8  = __attribute__((ext_vector_type(8))) short;

__device__ __forceinline__ f32x16 mfma32(s16x8 a, s16x8 b, f32x16 c) {
    return __builtin_amdgcn_mfma_f32_32x32x16_bf16(a, b, c, 0, 0, 0);
}

__device__ __forceinline__ unsigned short bf16bits(float x) {
    union { __hip_bfloat16 h; unsigned short s; } cv;
    cv.h = __float2bfloat16(x);
    return cv.s;
}
__device__ __forceinline__ unsigned pk_bf16(float lo, float hi) {
    return (unsigned)bf16bits(lo) | ((unsigned)bf16bits(hi) << 16);
}

__device__ __forceinline__ float fast_exp2(float x) {
#if __has_builtin(__builtin_amdgcn_exp2f)
    return __builtin_amdgcn_exp2f(x);
#else
    return __expf(x * 0.6931471805599453f);
#endif
}

// pi permutation within a 32-key group (involution): swap 4-7<->8-11, 20-23<->24-27.
__device__ __forceinline__ int kperm(int g) {
    const int m = g & 12;
    return (m == 4 || m == 8) ? (g ^ 12) : g;
}

// ---------------- QKV projection (MFMA) ---------------- (byte-identical to round 10-15)
__global__ __launch_bounds__(256) void qkv_proj_kernel(
    const float* __restrict__ x,
    const float* __restrict__ Wq, const float* __restrict__ Wk, const float* __restrict__ Wv,
    const float* __restrict__ bq, const float* __restrict__ bk, const float* __restrict__ bv,
    __hip_bfloat16* __restrict__ q_ws, __hip_bfloat16* __restrict__ k_ws,
    __hip_bfloat16* __restrict__ v_ws)
{
    const int bid  = blockIdx.x;
    const int tile = bid & 7;
    const int pair = bid >> 3;
    const int b = pair >> 4, h = pair & 15;
    const int t = threadIdx.x;
    const int w = t >> 6, l = t & 63;
    const int lq = l & 31, hi = l >> 5;
    const int s0 = tile * 128;

    __shared__ __align__(16) char Xs[16384];   // X stage [128 s][128B], then Q out
    __shared__ __align__(16) char Kt[16384];   // K out  [128 s][128B]
    __shared__ __align__(16) char Vt[16384];   // V out transposed [64 e][256B]

    {
        const float* xb = x + (size_t)(b * SS + s0) * DM + h * DH;
        #pragma unroll
        for (int i = 0; i < 8; ++i) {
            const int c  = t + 256 * i;
            const int r  = c >> 4, cw = c & 15;
            float4 v4 = *reinterpret_cast<const float4*>(xb + (size_t)r * DM + cw * 4);
            uint2 p;
            p.x = pk_bf16(v4.x, v4.y);
            p.y = pk_bf16(v4.z, v4.w);
            *reinterpret_cast<uint2*>(Xs + r * 128 + ((cw * 8) ^ ((r & 7) << 4))) = p;
        }
    }
    __syncthreads();

    const int arow = w * 32 + lq;
    const int asw  = (arow & 7) << 4;
    s16x8 af[4];
    #pragma unroll
    for (int s = 0; s < 4; ++s)
        af[s] = *reinterpret_cast<const s16x8*>(Xs + arow * 128 + ((s * 32 + hi * 16) ^ asw));
    __syncthreads();   // Xs now free for reuse as Q-out tile

    #pragma unroll
    for (int m = 0; m < 3; ++m) {
        const float* Wm = (m == 0) ? Wq : (m == 1) ? Wk : Wv;
        const float* bm = (m == 0) ? bq : (m == 1) ? bk : bv;

        f32x16 a0, a1;
        #pragma unroll
        for (int r = 0; r < 16; ++r) { a0[r] = 0.0f; a1[r] = 0.0f; }

        #pragma unroll
        for (int s = 0; s < 4; ++s) {
            const float* wp0 = Wm + (size_t)(h * DH + lq) * DH + s * 16 + hi * 8;
            const float* wp1 = wp0 + 32 * DH;
            float4 wa0 = reinterpret_cast<const float4*>(wp0)[0];
            float4 wb0 = reinterpret_cast<const float4*>(wp0)[1];
            float4 wa1 = reinterpret_cast<const float4*>(wp1)[0];
            float4 wb1 = reinterpret_cast<const float4*>(wp1)[1];
            union { unsigned u[4]; s16x8 v; } bf0, bf1;
            bf0.u[0] = pk_bf16(wa0.x, wa0.y); bf0.u[1] = pk_bf16(wa0.z, wa0.w);
            bf0.u[2] = pk_bf16(wb0.x, wb0.y); bf0.u[3] = pk_bf16(wb0.z, wb0.w);
            bf1.u[0] = pk_bf16(wa1.x, wa1.y); bf1.u[1] = pk_bf16(wa1.z, wa1.w);
            bf1.u[2] = pk_bf16(wb1.x, wb1.y); bf1.u[3] = pk_bf16(wb1.z, wb1.w);
            a0 = mfma32(af[s], bf0.v, a0);
            a1 = mfma32(af[s], bf1.v, a1);
        }

        const float bias0 = bm[h * DH + lq];
        const float bias1 = bm[h * DH + 32 + lq];

        if (m < 2) {
            char* T = (m == 0) ? Xs : Kt;
            #pragma unroll
            for (int r = 0; r < 16; ++r) {
                const int row = w * 32 + (r & 3) + 8 * (r >> 2) + 4 * hi;
                const int sw  = (row & 7) << 4;
                *reinterpret_cast<unsigned short*>(T + row * 128 + ((lq * 2) ^ sw)) =
                    bf16bits(a0[r] + bias0);
                *reinterpret_cast<unsigned short*>(T + row * 128 + (((32 + lq) * 2) ^ sw)) =
                    bf16bits(a1[r] + bias1);
            }
        } else {
            #pragma unroll
            for (int g = 0; g < 4; ++g) {
                const int off = w * 64 + g * 16 + hi * 8;
                uint2 p0, p1;
                p0.x = pk_bf16(a0[4*g+0] + bias0, a0[4*g+1] + bias0);
                p0.y = pk_bf16(a0[4*g+2] + bias0, a0[4*g+3] + bias0);
                p1.x = pk_bf16(a1[4*g+0] + bias1, a1[4*g+1] + bias1);
                p1.y = pk_bf16(a1[4*g+2] + bias1, a1[4*g+3] + bias1);
                *reinterpret_cast<uint2*>(Vt + lq * 256 + (off ^ ((lq & 7) << 4))) = p0;
                *reinterpret_cast<uint2*>(Vt + (32 + lq) * 256 + (off ^ (((32 + lq) & 7) << 4))) = p1;
            }
        }
    }
    __syncthreads();

    #pragma unroll
    for (int i = 0; i < 4; ++i) {
        const int c   = t + 256 * i;
        const int row = c >> 3, cc = c & 7;
        const int off = row * 128 + ((cc * 16) ^ ((row & 7) << 4));
        s16x8 qv = *reinterpret_cast<const s16x8*>(Xs + off);
        *reinterpret_cast<s16x8*>(q_ws + ((size_t)pair * SS + s0 + row) * DH + cc * 8) = qv;
        s16x8 kv = *reinterpret_cast<const s16x8*>(Kt + off);
        *reinterpret_cast<s16x8*>(k_ws + ((size_t)pair * SS + s0 + row) * DH + cc * 8) = kv;
    }
    #pragma unroll
    for (int i = 0; i < 4; ++i) {
        const int c   = t + 256 * i;
        const int row = c >> 4, cc = c & 15;
        s16x8 vv = *reinterpret_cast<const s16x8*>(
            Vt + row * 256 + ((cc * 16) ^ ((row & 7) << 4)));
        *reinterpret_cast<s16x8*>(v_ws + ((size_t)pair * DH + row) * SS + s0 + cc * 8) = vv;
    }
}

// ---------------- Flash attention: global-direct + REGISTER double-buffer prefetch ----------------
// Round-13 structure (validated): grid 2048 = 64 pairs x 32 q-groups (XCD swizzle,
// 8 pairs/XCD -> K/V/Q L2-resident); block 256 = 4 waves = 4 KV quarters of the same
// 32 q-rows; zero inner barriers. Round-13's defect was dependent L2 loads at point of
// use (73 us, all pipes idle). Fix: K-frags for group g+1 issued one iteration early
// (~800 cyc cover), V-frags for group g issued before QK^T (~400 cyc cover).
// Static-max softmax (round-15 validated) + max-free 4-way merge (sum partials).
__global__ __launch_bounds__(256, 3) void attn_kernel(
    const __hip_bfloat16* __restrict__ q_ws,
    const __hip_bfloat16* __restrict__ k_ws,
    const __hip_bfloat16* __restrict__ v_ws,
    float* __restrict__ out)
{
    const int bid  = blockIdx.x;
    const int lbid = (bid & 7) * 256 + (bid >> 3);   // XCD swizzle (2048 % 8 == 0)
    const int qg   = lbid & 31;
    const int pair = lbid >> 5;
    const int b = pair >> 4, h = pair & 15;
    const int t = threadIdx.x;
    const int p = t >> 6, l = t & 63;
    const int lq = l & 31, hi = l >> 5;

    __shared__ __align__(16) char smem[16896];   // 2 x (O 8192B + l 256B)

    // Q fragments
    const __hip_bfloat16* qp = q_ws + ((size_t)pair * SS + qg * 32 + lq) * DH + hi * 8;
    s16x8 qf[4];
    #pragma unroll
    for (int s5 = 0; s5 < 4; ++s5)
        qf[s5] = *reinterpret_cast<const s16x8*>(qp + s5 * 16);

    // K/V per-lane bases (round-13 validated formulas; pi on K read)
    const __hip_bfloat16* kp  = k_ws + ((size_t)pair * SS + kperm(lq)) * DH + hi * 8;
    const __hip_bfloat16* vp0 = v_ws + ((size_t)pair * DH + lq) * SS + hi * 8;
    const __hip_bfloat16* vp1 = vp0 + (size_t)32 * SS;

    f32x16 o0, o1, lacc;
    #pragma unroll
    for (int r = 0; r < 16; ++r) { o0[r] = 0.0f; o1[r] = 0.0f; lacc[r] = 0.0f; }
    const float cml = 0.18033688011112042f;  // log2(e)/8 : folds 1/sqrt(64) + exp2 domain

    // register double-buffer: kc = K frags of current group, kn = next group
    s16x8 kc[4], kn[4], vv[4];
    {
        const __hip_bfloat16* kg0 = kp + (size_t)(p * 8) * 32 * DH;
        #pragma unroll
        for (int s5 = 0; s5 < 4; ++s5)
            kc[s5] = *reinterpret_cast<const s16x8*>(kg0 + s5 * 16);
    }

    #pragma unroll
    for (int g8 = 0; g8 < 8; ++g8) {
        const int g = p * 8 + g8;

        // issue V loads for THIS group now (consumed after softmax, ~400 cyc away)
        const __hip_bfloat16* vg0 = vp0 + g * 32;
        const __hip_bfloat16* vg1 = vp1 + g * 32;
        vv[0] = *reinterpret_cast<const s16x8*>(vg0);        // s5=0, d=lq
        vv[1] = *reinterpret_cast<const s16x8*>(vg0 + 16);   // s5=1, d=lq
        vv[2] = *reinterpret_cast<const s16x8*>(vg1);        // s5=0, d=32+lq
        vv[3] = *reinterpret_cast<const s16x8*>(vg1 + 16);   // s5=1, d=32+lq

        // issue K loads for NEXT group (consumed next iteration, ~800 cyc away)
        if (g8 < 7) {
            const __hip_bfloat16* kg1 = kp + (size_t)(g + 1) * 32 * DH;
            #pragma unroll
            for (int s5 = 0; s5 < 4; ++s5)
                kn[s5] = *reinterpret_cast<const s16x8*>(kg1 + s5 * 16);
        }

        // QK^T (swapped) with the PREFETCHED kc
        f32x16 sc;
        #pragma unroll
        for (int r = 0; r < 16; ++r) sc[r] = 0.0f;
        #pragma unroll
        for (int s5 = 0; s5 < 4; ++s5)
            sc = mfma32(kc[s5], qf[s5], sc);

        // static-max softmax: P = exp2(s*cml), per-reg sum accumulation
        #pragma unroll
        for (int r = 0; r < 16; ++r) {
            sc[r] = fast_exp2(sc[r] * cml);
            lacc[r] += sc[r];
        }

        // P -> A-frags (pure in-lane; pi-aligned) + PV with vv
        union { unsigned u[4]; s16x8 v; } af0, af1;
        af0.u[0] = pk_bf16(sc[0], sc[1]);   af0.u[1] = pk_bf16(sc[2], sc[3]);
        af0.u[2] = pk_bf16(sc[4], sc[5]);   af0.u[3] = pk_bf16(sc[6], sc[7]);
        af1.u[0] = pk_bf16(sc[8], sc[9]);   af1.u[1] = pk_bf16(sc[10], sc[11]);
        af1.u[2] = pk_bf16(sc[12], sc[13]); af1.u[3] = pk_bf16(sc[14], sc[15]);

        o0 = mfma32(af0.v, vv[0], o0);
        o0 = mfma32(af1.v, vv[1], o0);
        o1 = mfma32(af0.v, vv[2], o1);
        o1 = mfma32(af1.v, vv[3], o1);

        // rotate register buffer (full unroll -> pure renames)
        #pragma unroll
        for (int s5 = 0; s5 < 4; ++s5) kc[s5] = kn[s5];
    }

    // ONE final sum reduction: tree over 16 regs + cross-half shfl (per query lq)
    float ts[16];
    #pragma unroll
    for (int r = 0; r < 16; ++r) ts[r] = lacc[r];
    #pragma unroll
    for (int s = 8; s >= 1; s >>= 1)
        #pragma unroll
        for (int r = 0; r < 8; ++r)
            if (r < s) ts[r] += ts[r + s];
    float lsum = ts[0] + __shfl_xor(ts[0], 32);

    // ---- max-free 4-way merge via LDS (tree: 0<-1, 2<-3, then 0<-2); sums only ----
    float* O0 = reinterpret_cast<float*>(smem);
    float* M0 = reinterpret_cast<float*>(smem + 8192);
    float* O1 = reinterpret_cast<float*>(smem + 8448);
    float* M1 = reinterpret_cast<float*>(smem + 16640);

    if (p == 1 || p == 3) {
        float* O = (p == 1) ? O0 : O1;
        float* M = (p == 1) ? M0 : M1;
        #pragma unroll
        for (int r = 0; r < 16; ++r) {
            const int qr = (r & 3) + 8 * (r >> 2) + 4 * hi;
            O[qr * 64 + lq]      = o0[r];
            O[qr * 64 + 32 + lq] = o1[r];
        }
        if (hi == 0) M[lq] = lsum;
    }
    __syncthreads();
    if (p == 0 || p == 2) {
        float* O = (p == 0) ? O0 : O1;
        float* M = (p == 0) ? M0 : M1;
        #pragma unroll
        for (int r = 0; r < 16; ++r) {
            const int qr = (r & 3) + 8 * (r >> 2) + 4 * hi;
            o0[r] += O[qr * 64 + lq];
            o1[r] += O[qr * 64 + 32 + lq];
        }
        lsum += M[lq];
    }
    __syncthreads();
    if (p == 2) {
        #pragma unroll
        for (int r = 0; r < 16; ++r) {
            const int qr = (r & 3) + 8 * (r >> 2) + 4 * hi;
            O1[qr * 64 + lq]      = o0[r];
            O1[qr * 64 + 32 + lq] = o1[r];
        }
        if (hi == 0) M1[lq] = lsum;
    }
    __syncthreads();
    if (p == 0) {
        const float inv = 1.0f / (lsum + M1[lq]);    // per query lq
        #pragma unroll
        for (int r = 0; r < 16; ++r) {
            const int qr = (r & 3) + 8 * (r >> 2) + 4 * hi;
            const float invr = __shfl(inv, qr);      // remap to query qr (validated)
            float* op = out + ((size_t)b * SS + qg * 32 + qr) * DM + h * DH + lq;
            op[0]  = (o0[r] + O1[qr * 64 + lq])      * invr;
            op[32] = (o1[r] + O1[qr * 64 + 32 + lq]) * invr;
        }
    }
}

extern "C" void kernel_launch(void* const* d_in, const int* in_sizes, int n_in,
                              void* d_out, int out_size, void* d_ws, size_t ws_size,
                              hipStream_t stream) {
    const float* x  = (const float*)d_in[0];
    const float* Wq = (const float*)d_in[1];
    const float* Wk = (const float*)d_in[2];
    const float* Wv = (const float*)d_in[3];
    const float* bq = (const float*)d_in[4];
    const float* bk = (const float*)d_in[5];
    const float* bv = (const float*)d_in[6];
    float* out = (float*)d_out;

    __hip_bfloat16* q_ws = (__hip_bfloat16*)d_ws;
    __hip_bfloat16* k_ws = q_ws + (size_t)BB * HH * SS * DH;
    __hip_bfloat16* v_ws = k_ws + (size_t)BB * HH * SS * DH;

    qkv_proj_kernel<<<dim3(BB * HH * (SS / 128)), dim3(256), 0, stream>>>(
        x, Wq, Wk, Wv, bq, bk, bv, q_ws, k_ws, v_ws);
    attn_kernel<<<dim3(BB * HH * (SS / 32)), dim3(256), 0, stream>>>(
        q_ws, k_ws, v_ws, out);
}